// Round 15
// baseline (645.061 us; speedup 1.0000x reference)
//
#include <hip/hip_runtime.h>
#include <hip/hip_bf16.h>

typedef __attribute__((ext_vector_type(8))) short bf16x8;
typedef __attribute__((ext_vector_type(4))) float f32x4;

#define B_SZ   1024
#define T_SZ   128
#define L_SZ   256
#define F_SZ   784
#define M_TOT  (B_SZ * T_SZ)            // 131072
#define BK     32
#define KSTEPS 25                       // ceil(784/32), tail zero-padded

#define WPRE_ELEMS (KSTEPS * 4 * L_SZ)  // 25600 bf16x8 elements
#define WPRE_BYTES (WPRE_ELEMS * 16)    // 409600
#define CDIFF_ELEMS (T_SZ * L_SZ)       // 32768
#define WS_NEED (WPRE_BYTES + CDIFF_ELEMS * 4)

// v14 geometry: f32 stage window = 32 rows x 160 f32 (5 K-steps), pitch 656B
#define ROWB    656                     // 640 data + 16 pad (bank rotation)
#define ABF_OFF 21504                   // f32S = 21 x 1024B DMA chunks
#define SMEM_SZ 38400                   // f32S 21504 + Ot16 16896 (Abf inside)
#define STRIPB  100352                  // 32 rows * 3136 B: x stride per strip

__device__ __forceinline__ unsigned short f2bf(float f) {
    __hip_bfloat16 h = __float2bfloat16(f);   // RTNE
    return *reinterpret_cast<unsigned short*>(&h);
}

// ---------------- prep: W -> bf16 MFMA-fragment layout; cdiff = c0 - c1 ----
// wpre[ks][kgrp][leaf] : bf16x8 = W[leaf][ks*32+kgrp*8 .. +8), 0-padded tail
__global__ __launch_bounds__(256) void dn_prep(
    const float* __restrict__ W, const float* __restrict__ contrib,
    unsigned short* __restrict__ wpre, float* __restrict__ cdiff)
{
    const int gid = blockIdx.x * 256 + threadIdx.x;
    if (gid < WPRE_ELEMS) {
        const int leaf = gid & 255;
        const int kg   = (gid >> 8) & 3;
        const int ks   = gid >> 10;
        const int k0   = ks * BK + kg * 8;
        bf16x8 v;
        #pragma unroll
        for (int j = 0; j < 8; ++j) {
            const int k = k0 + j;
            const float f = (k < F_SZ) ? W[(size_t)leaf * F_SZ + k] : 0.f;
            v[j] = (short)f2bf(f);
        }
        *reinterpret_cast<bf16x8*>(wpre + (size_t)gid * 8) = v;
    } else {
        const int cid = gid - WPRE_ELEMS;
        if (cid < CDIFF_ELEMS)
            cdiff[cid] = contrib[(size_t)cid * 2] - contrib[(size_t)cid * 2 + 1];
    }
}

// ---------------- v14: persistent strips + cross-strip DMA prefetch --------
// Grid 1024, 512 thr (8 waves, wave tile 32x32), each block owns 4 strips of
// 32 rows (128 consecutive rows). v13's window pipeline per strip, plus: at
// the w==3 boundary (f32S free), ISSUE the DMA for the NEXT STRIP's window 0
// -> it lands under window-4 compute + the epilogue, so the x HBM stream
// stays busy across strip boundaries and each strip prologue is just
// barrier + CVT. All waits are full drains -> plain __syncthreads is correct
// everywhere (no vmcnt counting, no compiler fights — v13-verified).
// LDS: f32S [0,21504) | Abf bf16 [21504,32064) | Ot16 epilogue [21504,38400)
// (Abf/Ot16 share, disjoint in time). 38.4 KB -> 3 blocks/CU (24 waves).
// Epilogue = 16-row half-passes, full-line contiguous stores.

#define GLDS(g, l)                                                           \
    __builtin_amdgcn_global_load_lds(                                        \
        (const __attribute__((address_space(1))) void*)(g),                  \
        (__attribute__((address_space(3))) void*)(l), 16, 0, 0)

__global__ __launch_bounds__(512, 6) void dn_fused14(
    const float* __restrict__ x, const unsigned short* __restrict__ wpre,
    const float* __restrict__ bias, const float* __restrict__ cdiff,
    float* __restrict__ out)
{
    __shared__ __align__(16) unsigned char smem[SMEM_SZ];

    const int tid  = threadIdx.x;
    const int lane = tid & 63;
    const int wid  = tid >> 6;          // 0..7 -> 32-col group
    const int lr   = lane & 15;
    const int kseg = lane >> 4;         // 0..3

    const int bid      = blockIdx.x;
    const int colBase  = wid * 32;
    const char* xbase0 = (const char*)x + (size_t)bid * 128 * 3136;

    // ISSUE(w, soff): stage window w of the strip at byte offset soff into
    // f32S. Addresses recomputed inline (saves ~12 persistent VGPRs).
    // Window 4 tail: source col valid iff colb<576; else clamp to row start
    // (values don't-care — wpre zero-pads k>=784).
    #define ISSUE(w, soff) do {                                              \
        _Pragma("unroll")                                                    \
        for (int _jj = 0; _jj < 3; ++_jj) {                                  \
            const int _j = wid + 8 * _jj;                                    \
            if (_j < 21) {                                                   \
                const unsigned _s    = _j * 1024 + lane * 16;                \
                const unsigned _row  = _s / ROWB;                            \
                const unsigned _colb = _s - _row * ROWB;                     \
                const bool     _ok   = (_row < 32) && (_colb < 640);         \
                const unsigned _rcl  = (_row < 32) ? _row : 0;               \
                const char* _base = xbase0 + (soff) + (size_t)_rcl * 3136;   \
                const char* _src;                                            \
                if ((w) < 4) _src = _base + (_ok ? _colb : 0) + (w) * 640;   \
                else _src = _base + ((_ok && _colb < 576) ? 2560 + _colb : 0);\
                GLDS(_src, smem + _j * 1024);                                \
            }                                                                \
        }                                                                    \
    } while (0)

    // CVT: f32S window -> Abf bf16 tile (each element converted once)
    #define CVT() do {                                                       \
        _Pragma("unroll")                                                    \
        for (int _h = 0; _h < 2; ++_h) {                                     \
            const int _c = tid + _h * 512;                                   \
            if (_c < 640) {                                                  \
                const int _row = _c / 20;                                    \
                const int _kc  = _c - _row * 20;                             \
                const f32x4 _lo = *reinterpret_cast<const f32x4*>(           \
                    smem + _row * ROWB + _kc * 32);                          \
                const f32x4 _hi = *reinterpret_cast<const f32x4*>(           \
                    smem + _row * ROWB + _kc * 32 + 16);                     \
                bf16x8 _v;                                                   \
                _Pragma("unroll")                                            \
                for (int _j = 0; _j < 4; ++_j) {                             \
                    _v[_j]     = (short)f2bf(_lo[_j]);                       \
                    _v[4 + _j] = (short)f2bf(_hi[_j]);                       \
                }                                                            \
                *reinterpret_cast<bf16x8*>(smem + ABF_OFF                    \
                    + (_kc * 33 + _row) * 16) = _v;                          \
            }                                                                \
        }                                                                    \
    } while (0)

    const unsigned short* wpb = wpre + ((size_t)kseg * L_SZ + colBase + lr) * 8;
    typedef float OtRow16[264];
    OtRow16* Ot = reinterpret_cast<OtRow16*>(smem + ABF_OFF);
    const int erow = tid >> 5;          // 0..15
    const int ecol = (tid & 31) * 8;    // 0..248
    const size_t GOFF = (size_t)M_TOT * L_SZ;

    // kernel prologue: stage strip 0, window 0
    ISSUE(0, 0);

    for (int st = 0; st < 4; ++st) {
        const int    rowBase = bid * 128 + st * 32;
        const size_t soff    = (size_t)st * STRIPB;

        __syncthreads();                // f32S(w0) landed; prev Ot16 reads done
        CVT();
        __syncthreads();                // Abf ready, f32S free
        ISSUE(1, soff);

        f32x4 acc[2][2];
        #pragma unroll
        for (int mi = 0; mi < 2; ++mi)
            #pragma unroll
            for (int ni = 0; ni < 2; ++ni)
                acc[mi][ni] = (f32x4){0.f, 0.f, 0.f, 0.f};

        bf16x8 wcur[2], wnxt[2];
        wcur[0] = *reinterpret_cast<const bf16x8*>(wpb);
        wcur[1] = *reinterpret_cast<const bf16x8*>(wpb + 128);

        #pragma unroll
        for (int w = 0; w < 5; ++w) {
            #pragma unroll
            for (int i = 0; i < 5; ++i) {
                const int ks = w * 5 + i;
                if (ks + 1 < KSTEPS) {
                    wnxt[0] = *reinterpret_cast<const bf16x8*>(wpb + (size_t)(ks + 1) * 8192);
                    wnxt[1] = *reinterpret_cast<const bf16x8*>(wpb + (size_t)(ks + 1) * 8192 + 128);
                }
                bf16x8 af[2];
                #pragma unroll
                for (int m = 0; m < 2; ++m)
                    af[m] = *reinterpret_cast<const bf16x8*>(
                        smem + ABF_OFF + (((i * 4 + kseg) * 33) + m * 16 + lr) * 16);

                acc[0][0] = __builtin_amdgcn_mfma_f32_16x16x32_bf16(af[0], wcur[0], acc[0][0], 0, 0, 0);
                acc[0][1] = __builtin_amdgcn_mfma_f32_16x16x32_bf16(af[0], wcur[1], acc[0][1], 0, 0, 0);
                acc[1][0] = __builtin_amdgcn_mfma_f32_16x16x32_bf16(af[1], wcur[0], acc[1][0], 0, 0, 0);
                acc[1][1] = __builtin_amdgcn_mfma_f32_16x16x32_bf16(af[1], wcur[1], acc[1][1], 0, 0, 0);
                wcur[0] = wnxt[0];
                wcur[1] = wnxt[1];
            }
            if (w < 4) {
                __syncthreads();        // Abf reads done + f32S(w+1) landed
                CVT();
                __syncthreads();        // Abf updated, f32S free
                if (w < 3)       ISSUE(w + 2, soff);
                else if (st < 3) ISSUE(0, soff + STRIPB);  // next strip w0
            }
        }
        __syncthreads();                // Abf reads done; prefetch drained

        // ---- epilogue: sp/gini via 16-row half-pass transpose ----
        float spv[2][2][4];
        #pragma unroll
        for (int ni = 0; ni < 2; ++ni) {
            const float bb = bias[colBase + ni * 16 + lr];
            #pragma unroll
            for (int mi = 0; mi < 2; ++mi)
                #pragma unroll
                for (int r = 0; r < 4; ++r)
                    spv[mi][ni][r] = fminf(fmaxf(acc[mi][ni][r] + bb, -1.f), 1.f);
        }

        #pragma unroll
        for (int h = 0; h < 2; ++h) {   // sp halves
            #pragma unroll
            for (int ni = 0; ni < 2; ++ni)
                #pragma unroll
                for (int r = 0; r < 4; ++r)
                    Ot[kseg * 4 + r][colBase + ni * 16 + lr] = spv[h][ni][r];
            __syncthreads();
            float* orow = out + (size_t)(rowBase + h * 16 + erow) * L_SZ + ecol;
            *reinterpret_cast<f32x4*>(orow)     = *reinterpret_cast<const f32x4*>(&Ot[erow][ecol]);
            *reinterpret_cast<f32x4*>(orow + 4) = *reinterpret_cast<const f32x4*>(&Ot[erow][ecol + 4]);
            __syncthreads();
        }
        #pragma unroll
        for (int h = 0; h < 2; ++h) {   // gini halves
            #pragma unroll
            for (int ni = 0; ni < 2; ++ni) {
                const int col = colBase + ni * 16 + lr;
                #pragma unroll
                for (int r = 0; r < 4; ++r) {
                    const int t = (rowBase + h * 16 + kseg * 4 + r) & (T_SZ - 1);
                    const float d  = spv[h][ni][r] * cdiff[t * L_SZ + col];
                    const float ed = __expf(d);
                    const float s2 = ed / (1.f + ed);
                    Ot[kseg * 4 + r][col] = fmaf(2.f * s2, 1.f - s2, 1.f);
                }
            }
            __syncthreads();
            float* orow = out + GOFF + (size_t)(rowBase + h * 16 + erow) * L_SZ + ecol;
            *reinterpret_cast<f32x4*>(orow)     = *reinterpret_cast<const f32x4*>(&Ot[erow][ecol]);
            *reinterpret_cast<f32x4*>(orow + 4) = *reinterpret_cast<const f32x4*>(&Ot[erow][ecol + 4]);
            if (h == 0 || st < 3) __syncthreads();  // protect Ot before reuse
        }
    }
    #undef ISSUE
    #undef CVT
}

// ---------------- v1 fallback (no workspace needed) ------------------------
__global__ __launch_bounds__(512) void dn_fused_v1(
    const float* __restrict__ x, const float* __restrict__ W,
    const float* __restrict__ bias, const float* __restrict__ contrib,
    float* __restrict__ out)
{
    __shared__ bf16x8 As[4][128];
    __shared__ bf16x8 Bs[4][L_SZ];

    const int tid    = threadIdx.x;
    const int lane   = tid & 63;
    const int wid    = tid >> 6;
    const int waveM  = wid >> 2;
    const int waveN  = wid & 3;
    const int blkRow = blockIdx.x * 128;
    const int ar = tid >> 2;
    const int ak = (tid & 3) * 8;
    const int wr = tid >> 1;
    const int wk = (tid & 1) * 16;
    const int laneRow = lane & 15;
    const int kgrp    = lane >> 4;

    f32x4 acc[4][4];
    #pragma unroll
    for (int i = 0; i < 4; ++i)
        #pragma unroll
        for (int j = 0; j < 4; ++j)
            acc[i][j] = (f32x4){0.f, 0.f, 0.f, 0.f};

    const float* xrow = x + (size_t)(blkRow + ar) * F_SZ;
    const float* wrow = W + (size_t)wr * F_SZ;
    const f32x4 zf = {0.f, 0.f, 0.f, 0.f};

    f32x4 xa0 = *reinterpret_cast<const f32x4*>(xrow + ak);
    f32x4 xa1 = *reinterpret_cast<const f32x4*>(xrow + ak + 4);
    f32x4 wa0 = *reinterpret_cast<const f32x4*>(wrow + wk);
    f32x4 wa1 = *reinterpret_cast<const f32x4*>(wrow + wk + 4);
    f32x4 wa2 = *reinterpret_cast<const f32x4*>(wrow + wk + 8);
    f32x4 wa3 = *reinterpret_cast<const f32x4*>(wrow + wk + 12);

    for (int ks = 0; ks < KSTEPS; ++ks) {
        bf16x8 av, wv0, wv1;
        #pragma unroll
        for (int j = 0; j < 4; ++j) {
            av[j]      = (short)f2bf(xa0[j]);
            av[4 + j]  = (short)f2bf(xa1[j]);
            wv0[j]     = (short)f2bf(wa0[j]);
            wv0[4 + j] = (short)f2bf(wa1[j]);
            wv1[j]     = (short)f2bf(wa2[j]);
            wv1[4 + j] = (short)f2bf(wa3[j]);
        }
        As[ak >> 3][ar] = av;
        Bs[wk >> 3][wr] = wv0;
        Bs[(wk >> 3) + 1][wr] = wv1;
        __syncthreads();

        if (ks + 1 < KSTEPS) {
            const int kb = (ks + 1) * BK;
            if (kb + ak < F_SZ) {
                xa0 = *reinterpret_cast<const f32x4*>(xrow + kb + ak);
                xa1 = *reinterpret_cast<const f32x4*>(xrow + kb + ak + 4);
            } else { xa0 = zf; xa1 = zf; }
            if (kb + wk < F_SZ) {
                wa0 = *reinterpret_cast<const f32x4*>(wrow + kb + wk);
                wa1 = *reinterpret_cast<const f32x4*>(wrow + kb + wk + 4);
                wa2 = *reinterpret_cast<const f32x4*>(wrow + kb + wk + 8);
                wa3 = *reinterpret_cast<const f32x4*>(wrow + kb + wk + 12);
            } else { wa0 = zf; wa1 = zf; wa2 = zf; wa3 = zf; }
        }

        bf16x8 af[4], bfv[4];
        #pragma unroll
        for (int mi = 0; mi < 4; ++mi)
            af[mi] = As[kgrp][waveM * 64 + mi * 16 + laneRow];
        #pragma unroll
        for (int ni = 0; ni < 4; ++ni)
            bfv[ni] = Bs[kgrp][waveN * 64 + ni * 16 + laneRow];
        #pragma unroll
        for (int mi = 0; mi < 4; ++mi)
            #pragma unroll
            for (int ni = 0; ni < 4; ++ni)
                acc[mi][ni] = __builtin_amdgcn_mfma_f32_16x16x32_bf16(
                    af[mi], bfv[ni], acc[mi][ni], 0, 0, 0);
        __syncthreads();
    }

    const size_t GOFF  = (size_t)M_TOT * L_SZ;
    const int    rbase = waveM * 64 + (lane >> 4) * 4;
    const int    cbase = waveN * 64 + laneRow;
    #pragma unroll
    for (int ni = 0; ni < 4; ++ni) {
        const int col = cbase + ni * 16;
        const float bb = bias[col];
        #pragma unroll
        for (int mi = 0; mi < 4; ++mi) {
            #pragma unroll
            for (int r = 0; r < 4; ++r) {
                const int m = blkRow + rbase + mi * 16 + r;
                const int t = m & (T_SZ - 1);
                float v  = acc[mi][ni][r] + bb;
                float sp = fminf(fmaxf(v, -1.f), 1.f);
                const float* cp = contrib + (size_t)(t * L_SZ + col) * 2;
                const float d  = sp * (cp[0] - cp[1]);
                const float ed = __expf(d);
                const float s  = ed / (1.f + ed);
                const float g  = fmaf(2.f * s, 1.f - s, 1.f);
                const size_t o = (size_t)m * L_SZ + col;
                out[o]        = sp;
                out[GOFF + o] = g;
            }
        }
    }
}

extern "C" void kernel_launch(void* const* d_in, const int* in_sizes, int n_in,
                              void* d_out, int out_size, void* d_ws, size_t ws_size,
                              hipStream_t stream) {
    const float* x       = (const float*)d_in[0];
    const float* W       = (const float*)d_in[1];
    const float* bias    = (const float*)d_in[2];
    const float* contrib = (const float*)d_in[3];
    float* out = (float*)d_out;

    if (ws_size >= (size_t)WS_NEED && d_ws != nullptr) {
        unsigned short* wpre  = (unsigned short*)d_ws;
        float*          cdiff = (float*)((char*)d_ws + WPRE_BYTES);
        const int prep_threads = WPRE_ELEMS + CDIFF_ELEMS;
        dn_prep<<<(prep_threads + 255) / 256, 256, 0, stream>>>(W, contrib, wpre, cdiff);
        dn_fused14<<<1024, 512, 0, stream>>>(x, wpre, bias, cdiff, out);
    } else {
        dn_fused_v1<<<M_TOT / 128, 512, 0, stream>>>(x, W, bias, contrib, out);
    }
}

// Round 16
// 178.911 us; speedup vs baseline: 3.6055x; 3.6055x over previous
//
#include <hip/hip_runtime.h>
#include <hip/hip_bf16.h>

typedef __attribute__((ext_vector_type(8))) short bf16x8;
typedef __attribute__((ext_vector_type(4))) float f32x4;

#define B_SZ   1024
#define T_SZ   128
#define L_SZ   256
#define F_SZ   784
#define M_TOT  (B_SZ * T_SZ)            // 131072
#define BK     32
#define KSTEPS 25                       // ceil(784/32), tail zero-padded
#define KCHUNKS 100                     // KSTEPS*4 chunks of 8 k-values
#define BROWS  32                       // rows per block

#define WPRE_ELEMS (KSTEPS * 4 * L_SZ)  // 25600 bf16x8 elements
#define WPRE_BYTES (WPRE_ELEMS * 16)    // 409600
#define CDIFF_ELEMS (T_SZ * L_SZ)       // 32768
#define WS_NEED (WPRE_BYTES + CDIFF_ELEMS * 4)

__device__ __forceinline__ unsigned short f2bf(float f) {
    __hip_bfloat16 h = __float2bfloat16(f);   // RTNE
    return *reinterpret_cast<unsigned short*>(&h);
}

// ---------------- prep: W -> bf16 MFMA-fragment layout; cdiff = c0 - c1 ----
// wpre[ks][kgrp][leaf] : bf16x8 = W[leaf][ks*32+kgrp*8 .. +8), 0-padded tail
__global__ __launch_bounds__(256) void dn_prep(
    const float* __restrict__ W, const float* __restrict__ contrib,
    unsigned short* __restrict__ wpre, float* __restrict__ cdiff)
{
    const int gid = blockIdx.x * 256 + threadIdx.x;
    if (gid < WPRE_ELEMS) {
        const int leaf = gid & 255;
        const int kg   = (gid >> 8) & 3;
        const int ks   = gid >> 10;
        const int k0   = ks * BK + kg * 8;
        bf16x8 v;
        #pragma unroll
        for (int j = 0; j < 8; ++j) {
            const int k = k0 + j;
            const float f = (k < F_SZ) ? W[(size_t)leaf * F_SZ + k] : 0.f;
            v[j] = (short)f2bf(f);
        }
        *reinterpret_cast<bf16x8*>(wpre + (size_t)gid * 8) = v;
    } else {
        const int cid = gid - WPRE_ELEMS;
        if (cid < CDIFF_ELEMS)
            cdiff[cid] = contrib[(size_t)cid * 2] - contrib[(size_t)cid * 2 + 1];
    }
}

// ---------------- v8 (measured best: 178.8 us): ----------------------------
// Block = 32 rows x 256 cols, 16 waves (1024 thr), wave tile 32 rows x 16
// cols (2 MFMA + 2 LDS A-reads + 1 W-load per K-step). 51.2 KB LDS ->
// 2 blocks/CU, 32 waves/CU (100% slots). Contiguous flat staging (1KB/lane
// global_load_dwordx4), XOR-swizzled bf16 LDS tile, K-loop with 1-deep W
// L2 prefetch, LDS-transpose epilogue with full-line contiguous stores.
__global__ __launch_bounds__(1024, 2) void dn_fused8(
    const float* __restrict__ x, const unsigned short* __restrict__ wpre,
    const float* __restrict__ bias, const float* __restrict__ cdiff,
    float* __restrict__ out)
{
    __shared__ __align__(16) unsigned char smem[KCHUNKS * BROWS * 16]; // 51.2 KB
    bf16x8* As = reinterpret_cast<bf16x8*>(smem);
    typedef float OtRow[264];                    // +8 pad: bank rotation/row
    OtRow* Ot = reinterpret_cast<OtRow*>(smem);

    const int tid  = threadIdx.x;
    const int lane = tid & 63;
    const int wid  = tid >> 6;          // 0..15 -> 16-col group
    const int lr   = lane & 15;
    const int kseg = lane >> 4;         // 0..3

    const int rowBase = blockIdx.x * BROWS;
    const int colBase = wid * 16;

    // ---- stage x tile (32 x 784 f32 -> bf16 LDS), contiguous reads ----
    #pragma unroll
    for (int it = 0; it < 4; ++it) {
        const int i = it * 1024 + tid;          // flat chunk id
        if (i < BROWS * KCHUNKS) {
            const int row = i / KCHUNKS;        // 0..31
            const int kc  = i - row * KCHUNKS;  // 0..99
            bf16x8 v;
            if (kc < 98) {                      // k in [kc*8, kc*8+8)
                const float* p = x + (size_t)(rowBase + row) * F_SZ + kc * 8;
                const f32x4 lo = *reinterpret_cast<const f32x4*>(p);
                const f32x4 hi = *reinterpret_cast<const f32x4*>(p + 4);
                #pragma unroll
                for (int j = 0; j < 4; ++j) {
                    v[j]     = (short)f2bf(lo[j]);
                    v[4 + j] = (short)f2bf(hi[j]);
                }
            } else {                            // zero-pad k >= 784
                #pragma unroll
                for (int j = 0; j < 8; ++j) v[j] = 0;
            }
            As[kc * BROWS + (row ^ (kc & 7))] = v;
        }
    }
    __syncthreads();

    // ---- K-loop: A from LDS, W streamed from L2 (1-step lookahead) ----
    const unsigned short* wpb = wpre + ((size_t)kseg * L_SZ + colBase + lr) * 8;

    f32x4 acc[2];
    acc[0] = (f32x4){0.f, 0.f, 0.f, 0.f};
    acc[1] = (f32x4){0.f, 0.f, 0.f, 0.f};

    bf16x8 wcur = *reinterpret_cast<const bf16x8*>(wpb);
    bf16x8 wnxt;

    #pragma unroll
    for (int ks = 0; ks < KSTEPS; ++ks) {
        if (ks + 1 < KSTEPS)
            wnxt = *reinterpret_cast<const bf16x8*>(wpb + (size_t)(ks + 1) * 8192);

        const int kcr = ks * 4 + kseg;
        const bf16x8 a0 = As[kcr * BROWS + (lr ^ (kcr & 7))];
        const bf16x8 a1 = As[kcr * BROWS + ((16 + lr) ^ (kcr & 7))];

        acc[0] = __builtin_amdgcn_mfma_f32_16x16x32_bf16(a0, wcur, acc[0], 0, 0, 0);
        acc[1] = __builtin_amdgcn_mfma_f32_16x16x32_bf16(a1, wcur, acc[1], 0, 0, 0);
        wcur = wnxt;
    }
    __syncthreads();   // all As reads done; smem becomes Ot

    // ---- sp in registers ----
    float spv[2][4];
    const float bb = bias[colBase + lr];
    #pragma unroll
    for (int mi = 0; mi < 2; ++mi)
        #pragma unroll
        for (int r = 0; r < 4; ++r)
            spv[mi][r] = fminf(fmaxf(acc[mi][r] + bb, -1.f), 1.f);

    const int erow = tid >> 5;          // 0..31
    const int ecol = (tid & 31) * 4;    // 0..124 (f32x4 chunks)
    const size_t GOFF = (size_t)M_TOT * L_SZ;
    float* orow = out + (size_t)(rowBase + erow) * L_SZ;

    // ---- pass 1: sp -> LDS transpose -> contiguous store ----
    #pragma unroll
    for (int mi = 0; mi < 2; ++mi)
        #pragma unroll
        for (int r = 0; r < 4; ++r)
            Ot[mi * 16 + kseg * 4 + r][colBase + lr] = spv[mi][r];
    __syncthreads();
    #pragma unroll
    for (int j = 0; j < 2; ++j) {
        const f32x4 v = *reinterpret_cast<const f32x4*>(&Ot[erow][ecol + 128 * j]);
        *reinterpret_cast<f32x4*>(orow + ecol + 128 * j) = v;
    }
    __syncthreads();

    // ---- pass 2: gini -> LDS transpose -> contiguous store ----
    {
        const int col = colBase + lr;
        #pragma unroll
        for (int mi = 0; mi < 2; ++mi)
            #pragma unroll
            for (int r = 0; r < 4; ++r) {
                const int t = (rowBase + mi * 16 + kseg * 4 + r) & (T_SZ - 1);
                const float d  = spv[mi][r] * cdiff[t * L_SZ + col];
                const float ed = __expf(d);
                const float s2 = ed / (1.f + ed);
                Ot[mi * 16 + kseg * 4 + r][col] = fmaf(2.f * s2, 1.f - s2, 1.f);
            }
    }
    __syncthreads();
    #pragma unroll
    for (int j = 0; j < 2; ++j) {
        const f32x4 v = *reinterpret_cast<const f32x4*>(&Ot[erow][ecol + 128 * j]);
        *reinterpret_cast<f32x4*>(orow + GOFF + ecol + 128 * j) = v;
    }
}

// ---------------- v1 fallback (no workspace needed) ------------------------
__global__ __launch_bounds__(512) void dn_fused_v1(
    const float* __restrict__ x, const float* __restrict__ W,
    const float* __restrict__ bias, const float* __restrict__ contrib,
    float* __restrict__ out)
{
    __shared__ bf16x8 As[4][128];
    __shared__ bf16x8 Bs[4][L_SZ];

    const int tid    = threadIdx.x;
    const int lane   = tid & 63;
    const int wid    = tid >> 6;
    const int waveM  = wid >> 2;
    const int waveN  = wid & 3;
    const int blkRow = blockIdx.x * 128;
    const int ar = tid >> 2;
    const int ak = (tid & 3) * 8;
    const int wr = tid >> 1;
    const int wk = (tid & 1) * 16;
    const int laneRow = lane & 15;
    const int kgrp    = lane >> 4;

    f32x4 acc[4][4];
    #pragma unroll
    for (int i = 0; i < 4; ++i)
        #pragma unroll
        for (int j = 0; j < 4; ++j)
            acc[i][j] = (f32x4){0.f, 0.f, 0.f, 0.f};

    const float* xrow = x + (size_t)(blkRow + ar) * F_SZ;
    const float* wrow = W + (size_t)wr * F_SZ;
    const f32x4 zf = {0.f, 0.f, 0.f, 0.f};

    f32x4 xa0 = *reinterpret_cast<const f32x4*>(xrow + ak);
    f32x4 xa1 = *reinterpret_cast<const f32x4*>(xrow + ak + 4);
    f32x4 wa0 = *reinterpret_cast<const f32x4*>(wrow + wk);
    f32x4 wa1 = *reinterpret_cast<const f32x4*>(wrow + wk + 4);
    f32x4 wa2 = *reinterpret_cast<const f32x4*>(wrow + wk + 8);
    f32x4 wa3 = *reinterpret_cast<const f32x4*>(wrow + wk + 12);

    for (int ks = 0; ks < KSTEPS; ++ks) {
        bf16x8 av, wv0, wv1;
        #pragma unroll
        for (int j = 0; j < 4; ++j) {
            av[j]      = (short)f2bf(xa0[j]);
            av[4 + j]  = (short)f2bf(xa1[j]);
            wv0[j]     = (short)f2bf(wa0[j]);
            wv0[4 + j] = (short)f2bf(wa1[j]);
            wv1[j]     = (short)f2bf(wa2[j]);
            wv1[4 + j] = (short)f2bf(wa3[j]);
        }
        As[ak >> 3][ar] = av;
        Bs[wk >> 3][wr] = wv0;
        Bs[(wk >> 3) + 1][wr] = wv1;
        __syncthreads();

        if (ks + 1 < KSTEPS) {
            const int kb = (ks + 1) * BK;
            if (kb + ak < F_SZ) {
                xa0 = *reinterpret_cast<const f32x4*>(xrow + kb + ak);
                xa1 = *reinterpret_cast<const f32x4*>(xrow + kb + ak + 4);
            } else { xa0 = zf; xa1 = zf; }
            if (kb + wk < F_SZ) {
                wa0 = *reinterpret_cast<const f32x4*>(wrow + kb + wk);
                wa1 = *reinterpret_cast<const f32x4*>(wrow + kb + wk + 4);
                wa2 = *reinterpret_cast<const f32x4*>(wrow + kb + wk + 8);
                wa3 = *reinterpret_cast<const f32x4*>(wrow + kb + wk + 12);
            } else { wa0 = zf; wa1 = zf; wa2 = zf; wa3 = zf; }
        }

        bf16x8 af[4], bfv[4];
        #pragma unroll
        for (int mi = 0; mi < 4; ++mi)
            af[mi] = As[kgrp][waveM * 64 + mi * 16 + laneRow];
        #pragma unroll
        for (int ni = 0; ni < 4; ++ni)
            bfv[ni] = Bs[kgrp][waveN * 64 + ni * 16 + laneRow];
        #pragma unroll
        for (int mi = 0; mi < 4; ++mi)
            #pragma unroll
            for (int ni = 0; ni < 4; ++ni)
                acc[mi][ni] = __builtin_amdgcn_mfma_f32_16x16x32_bf16(
                    af[mi], bfv[ni], acc[mi][ni], 0, 0, 0);
        __syncthreads();
    }

    const size_t GOFF  = (size_t)M_TOT * L_SZ;
    const int    rbase = waveM * 64 + (lane >> 4) * 4;
    const int    cbase = waveN * 64 + laneRow;
    #pragma unroll
    for (int ni = 0; ni < 4; ++ni) {
        const int col = cbase + ni * 16;
        const float bb = bias[col];
        #pragma unroll
        for (int mi = 0; mi < 4; ++mi) {
            #pragma unroll
            for (int r = 0; r < 4; ++r) {
                const int m = blkRow + rbase + mi * 16 + r;
                const int t = m & (T_SZ - 1);
                float v  = acc[mi][ni][r] + bb;
                float sp = fminf(fmaxf(v, -1.f), 1.f);
                const float* cp = contrib + (size_t)(t * L_SZ + col) * 2;
                const float d  = sp * (cp[0] - cp[1]);
                const float ed = __expf(d);
                const float s  = ed / (1.f + ed);
                const float g  = fmaf(2.f * s, 1.f - s, 1.f);
                const size_t o = (size_t)m * L_SZ + col;
                out[o]        = sp;
                out[GOFF + o] = g;
            }
        }
    }
}

extern "C" void kernel_launch(void* const* d_in, const int* in_sizes, int n_in,
                              void* d_out, int out_size, void* d_ws, size_t ws_size,
                              hipStream_t stream) {
    const float* x       = (const float*)d_in[0];
    const float* W       = (const float*)d_in[1];
    const float* bias    = (const float*)d_in[2];
    const float* contrib = (const float*)d_in[3];
    float* out = (float*)d_out;

    if (ws_size >= (size_t)WS_NEED && d_ws != nullptr) {
        unsigned short* wpre  = (unsigned short*)d_ws;
        float*          cdiff = (float*)((char*)d_ws + WPRE_BYTES);
        const int prep_threads = WPRE_ELEMS + CDIFF_ELEMS;
        dn_prep<<<(prep_threads + 255) / 256, 256, 0, stream>>>(W, contrib, wpre, cdiff);
        dn_fused8<<<M_TOT / BROWS, 1024, 0, stream>>>(x, wpre, bias, cdiff, out);
    } else {
        dn_fused_v1<<<M_TOT / 128, 512, 0, stream>>>(x, W, bias, contrib, out);
    }
}